// Round 1
// 50.249 us; speedup vs baseline: 1.0418x; 1.0418x over previous
//
#include <hip/hip_runtime.h>
#include <math.h>

#define DD 512
#define VV 512
#define CC 2048
#define TOPK 32
#define EPSF 1e-8f

// ws float layout:
// [0, 2048)       sims
// [2048, 2560)    q
// [2560, 2592)    top_idx (32 ints)

// Kernel 1: q[i] = tanhf(dot(W_k[i,:], query) + b[i]); one wave per row.
__global__ void k1_q(const float* __restrict__ qk, const float* __restrict__ Wk,
                     const float* __restrict__ bk, float* __restrict__ q) {
    int wave = threadIdx.x >> 6;
    int lane = threadIdx.x & 63;
    int row = blockIdx.x * 4 + wave;
    const float4* wrow = (const float4*)(Wk + (size_t)row * DD);
    const float4* qv = (const float4*)qk;
    float4 a0 = wrow[lane], b0 = qv[lane];
    float4 a1 = wrow[lane + 64], b1 = qv[lane + 64];
    float s = a0.x * b0.x + a0.y * b0.y + a0.z * b0.z + a0.w * b0.w
            + a1.x * b1.x + a1.y * b1.y + a1.z * b1.z + a1.w * b1.w;
    #pragma unroll
    for (int off = 32; off; off >>= 1) s += __shfl_down(s, off);
    if (lane == 0) q[row] = tanhf(s + bk[row]);
}

// Kernel 2: 1024 blocks x 256 threads. Block handles 2 c's, 2 waves per c
// (each wave covers 256 of the 512 d's -> 4 strided loads/lane).
// 16 waves/CU (2x the previous version) for more memory-level parallelism.
// q staged in LDS; assoc reads non-temporal (pure stream, zero reuse).
__global__ void k2_sims(const float* __restrict__ assoc, const float* __restrict__ q,
                        float* __restrict__ sims) {
    __shared__ float qs[DD];
    __shared__ float red[4][3];
    int t = threadIdx.x;
    int wv = t >> 6, lane = t & 63;
    qs[t] = q[t];
    qs[t + 256] = q[t + 256];
    __syncthreads();
    int c = blockIdx.x * 2 + (wv >> 1);
    int h = wv & 1;
    const float* base = assoc + (size_t)c * ((size_t)DD * VV) + (size_t)(h * 256) * VV;
    float d = 0.f, n = 0.f, nq = 0.f;
    #pragma unroll
    for (int j = 0; j < 4; ++j) {
        int dd = lane + 64 * j;
        float a = __builtin_nontemporal_load(base + (size_t)dd * VV);
        float qq = qs[h * 256 + dd];
        d += a * qq;
        n += a * a;
        nq += qq * qq;
    }
    #pragma unroll
    for (int off = 32; off; off >>= 1) {
        d += __shfl_down(d, off);
        n += __shfl_down(n, off);
        nq += __shfl_down(nq, off);
    }
    if (lane == 0) { red[wv][0] = d; red[wv][1] = n; red[wv][2] = nq; }
    __syncthreads();
    if (t < 2) {
        float dt  = red[2 * t][0] + red[2 * t + 1][0];
        float nt_ = red[2 * t][1] + red[2 * t + 1][1];
        float nqt = red[2 * t][2] + red[2 * t + 1][2];
        sims[blockIdx.x * 2 + t] =
            dt / (fmaxf(sqrtf(nqt), EPSF) * fmaxf(sqrtf(nt_), EPSF));
    }
}

// Kernel 3: exact top-k by rank counting, split across 32 blocks x 4 cp-segments.
__global__ void k3_topk(const float* __restrict__ sims_g, const float* __restrict__ usage,
                        int* __restrict__ top_idx, float* __restrict__ out) {
    __shared__ float sims[CC];
    __shared__ int pr[256];
    int t = threadIdx.x;
    for (int i = t; i < CC; i += 256) sims[i] = sims_g[i];
    __syncthreads();
    int lane = t & 63, seg = t >> 6;
    int c = blockIdx.x * 64 + lane;
    float mv = sims[c];
    int rank = 0;
    const float4* s4 = (const float4*)sims;
    int base4 = seg * 128;
    #pragma unroll 8
    for (int i = 0; i < 128; ++i) {
        float4 v = s4[base4 + i];
        int cp = (base4 + i) * 4;
        rank += (v.x > mv) || (v.x == mv && cp     < c);
        rank += (v.y > mv) || (v.y == mv && cp + 1 < c);
        rank += (v.z > mv) || (v.z == mv && cp + 2 < c);
        rank += (v.w > mv) || (v.w == mv && cp + 3 < c);
    }
    pr[t] = rank;
    __syncthreads();
    if (seg == 0) {
        int total = pr[lane] + pr[lane + 64] + pr[lane + 128] + pr[lane + 192];
        if (total < TOPK) {
            top_idx[total] = c;
            out[16384 + total] = mv * (1.0f + log1pf(usage[c]));  // confidences
            out[16416 + total] = mv;                              // top_sims
        }
    }
}

// Kernel 4: direct einsum. block = (k, 64-col stripe); 4 waves x 128 rows each.
// Loads batched 64-deep into registers before the FMA pass so each wave keeps
// >=64 loads in flight (covers HBM latency at full per-CU BW share).
__global__ void k4_direct(const float* __restrict__ assoc, const float* __restrict__ qv,
                          const int* __restrict__ top_idx, float* __restrict__ out) {
    __shared__ float qs[DD];
    __shared__ float red[256];
    int t = threadIdx.x;
    int kk = blockIdx.x >> 3, chunk = blockIdx.x & 7;
    int wv = t >> 6, lane = t & 63;
    int idx = top_idx[kk];
    qs[t] = qv[t];
    qs[t + 256] = qv[t + 256];
    __syncthreads();
    const float* base = assoc + (size_t)idx * ((size_t)DD * VV) + chunk * 64 + lane;
    int r0 = wv * 128;
    float s = 0.f;
    #pragma unroll
    for (int g = 0; g < 2; ++g) {
        float v[64];
        #pragma unroll
        for (int r = 0; r < 64; ++r)
            v[r] = __builtin_nontemporal_load(base + (size_t)(r0 + g * 64 + r) * VV);
        #pragma unroll
        for (int r = 0; r < 64; ++r)
            s += qs[r0 + g * 64 + r] * v[r];
    }
    red[t] = s;
    __syncthreads();
    if (t < 64)
        out[kk * 512 + chunk * 64 + t] = red[t] + red[64 + t] + red[128 + t] + red[192 + t];
}

extern "C" void kernel_launch(void* const* d_in, const int* in_sizes, int n_in,
                              void* d_out, int out_size, void* d_ws, size_t ws_size,
                              hipStream_t stream) {
    const float* qk    = (const float*)d_in[0];
    const float* Wk    = (const float*)d_in[1];
    const float* bk    = (const float*)d_in[2];
    const float* assoc = (const float*)d_in[3];
    const float* usage = (const float*)d_in[4];

    float* ws      = (float*)d_ws;
    float* sims    = ws;
    float* q       = ws + 2048;
    int*   top_idx = (int*)(ws + 2560);
    float* out     = (float*)d_out;

    k1_q     <<<128,  256, 0, stream>>>(qk, Wk, bk, q);
    k2_sims  <<<1024, 256, 0, stream>>>(assoc, q, sims);
    k3_topk  <<<32,   256, 0, stream>>>(sims, usage, top_idx, out);
    k4_direct<<<TOPK * 8, 256, 0, stream>>>(assoc, q, top_idx, out);
}